// Round 3
// baseline (424.824 us; speedup 1.0000x reference)
//
#include <hip/hip_runtime.h>
#include <math.h>

#define H_AA   20
#define H_PAD  22
#define EMB    484          // 22*22
#define KSZ    9
#define NB     8            // batch
#define NPOS   512          // n
#define KNBR   30           // k neighbors
#define SMUT   99
#define STOT   100          // SMUT + WT
#define ROWS   (NB*KNBR)    // 240
#define MROWS  241          // + background row
#define NTOT   968          // o(484) | att(484) fused N
#define KC     400          // real (unpadded) conv in-channels per tap

// ---------------------------------------------------------------------------
// Kernel 1: per-batch setup. jmap in LDS, mask+prefix-scan -> rowidx/mcount,
// pairs bucketed BY TAP: pairtap[tap][idx] = (row_global<<5 | j).
// cnttap zero-initialized by the memset that precedes this kernel.
// ---------------------------------------------------------------------------
__global__ void setup_kernel(const int* __restrict__ E_idx,
                             const int* __restrict__ mut_pos,
                             const float* __restrict__ etab,
                             int* __restrict__ rowidx_g,
                             int* __restrict__ mcount,
                             int* __restrict__ pairtap,
                             int* __restrict__ cnttap) {
    int b  = blockIdx.x;
    int mp = mut_pos[b];
    __shared__ int jmap[NPOS];
    __shared__ int wcnt[8], wbase[8];
    int t = threadIdx.x;                 // 512 threads
    jmap[t] = -1;
    __syncthreads();
    if (t < KNBR) {
        int nb = E_idx[(b * NPOS + mp) * KNBR + t];
        bool winner = true;
        for (int j2 = t + 1; j2 < KNBR; ++j2)
            if (E_idx[(b * NPOS + mp) * KNBR + j2] == nb) { winner = false; break; }
        if (winner) jmap[nb] = t;        // last-write-wins, unique per position
    }
    __syncthreads();
    int j = jmap[t];
    int f = 0;
    if (j >= 0) {
        float c0 = etab[(((size_t)(b * NPOS + mp)) * KNBR + j) * 400];
        f = (c0 != 0.0f) ? 1 : 0;        // mask = lin[:,:,0] != 0
    }
    unsigned long long bal = __ballot(f);
    int lane = t & 63, w = t >> 6;
    if (lane == 0) wcnt[w] = __popcll(bal);
    __syncthreads();
    if (t == 0) {
        int s = 0;
        for (int ww = 0; ww < 8; ++ww) { wbase[ww] = s; s += wcnt[ww]; }
        mcount[b] = s;
    }
    __syncthreads();
    int ridx = -1;
    if (f) ridx = wbase[w] + __popcll(bal & ((1ull << lane) - 1ull));
    rowidx_g[b * NPOS + t] = ridx;
    if (f) {
        int row = b * KNBR + ridx;       // global row id 0..239
        for (int d = -4; d <= 4; ++d) {
            int q = t + d;
            if (q < 0 || q >= NPOS) continue;
            int jq = jmap[q];
            if (jq < 0) continue;        // conv input needs scatter-presence, not mask
            int tap = d + 4;
            int idx = atomicAdd(&cnttap[tap], 1);
            pairtap[tap * 256 + idx] = (row << 5) | jq;
        }
    }
}

// ---------------------------------------------------------------------------
// Kernel 2: pack conv weights.  src W[out][in_pad 484][tap 9]  (c = in_pad*9+tap)
//  -> Wp[tap*400 + (rr*20+cc)][half*484 + out], pad channels dropped.
// LDS-tiled so both read and write are coalesced.
// ---------------------------------------------------------------------------
__global__ void pack_conv_kernel(const float* __restrict__ Wf,
                                 const float* __restrict__ Wa,
                                 float* __restrict__ Wp) {
    int half = blockIdx.z;
    const float* src = half ? Wa : Wf;
    int cb = blockIdx.x * 32;            // c_src tile (0..4355)
    int ob = blockIdx.y * 32;            // out tile  (0..483)
    __shared__ float tile[32][33];
    for (int yy = threadIdx.y; yy < 32; yy += 8) {
        int out = ob + yy, c = cb + threadIdx.x;
        if (out < EMB && c < EMB * KSZ)
            tile[yy][threadIdx.x] = src[(size_t)out * (EMB * KSZ) + c];
    }
    __syncthreads();
    for (int yy = threadIdx.y; yy < 32; yy += 8) {
        int c = cb + yy, out = ob + threadIdx.x;
        if (c < EMB * KSZ && out < EMB) {
            int tap = c % 9, in_pad = c / 9;
            int rr = in_pad / H_PAD, cc = in_pad % H_PAD;
            if (rr < H_AA && cc < H_AA) {
                int k = tap * KC + rr * H_AA + cc;
                Wp[(size_t)k * NTOT + half * EMB + out] = tile[threadIdx.x][yy];
            }
        }
    }
}

// ---------------------------------------------------------------------------
// Kernel 3: transpose W1,W2 (z selects) 484x484 -> [in][out]
// ---------------------------------------------------------------------------
__global__ void transpose_lin_kernel(const float* __restrict__ W1,
                                     const float* __restrict__ W2,
                                     float* __restrict__ W1t,
                                     float* __restrict__ W2t) {
    const float* src = blockIdx.z ? W2 : W1;
    float*       dst = blockIdx.z ? W2t : W1t;
    __shared__ float tile[32][33];
    int c0 = blockIdx.x * 32, r0 = blockIdx.y * 32;
    for (int ty = threadIdx.y; ty < 32; ty += 8) {
        int r = r0 + ty, c = c0 + threadIdx.x;
        if (r < EMB && c < EMB) tile[ty][threadIdx.x] = src[(size_t)r * EMB + c];
    }
    __syncthreads();
    for (int ty = threadIdx.y; ty < 32; ty += 8) {
        int c = c0 + ty, r = r0 + threadIdx.x;
        if (r < EMB && c < EMB) dst[(size_t)c * EMB + r] = tile[threadIdx.x][ty];
    }
}

// ---------------------------------------------------------------------------
// Kernel 4: conv GEMM, bucketed by tap.
//  grid.x = 9 taps * 15 chunks (16 pairs each), grid.y = 16 n-tiles (64 wide).
//  Per block: acc[4] f64 per thread (64 n-lanes x 4 row-groups), K=400 in
//  chunks of 16 staged in LDS; x-rows read directly from etab.
//  Bias folded into tap==4 (every row has exactly one tap-4 pair).
//  f64 atomicAdd into zero-initialized C[240][968].
// ---------------------------------------------------------------------------
__global__ void conv_gemm_kernel(const float* __restrict__ etab,
                                 const float* __restrict__ Wp,
                                 const float* __restrict__ b_f,
                                 const float* __restrict__ b_a,
                                 const int* __restrict__ mut_pos,
                                 const int* __restrict__ pairtap,
                                 const int* __restrict__ cnttap,
                                 double* __restrict__ C) {
    int tap   = blockIdx.x / 15;
    int chunk = blockIdx.x % 15;
    int cnt = cnttap[tap];
    if (chunk * 16 >= cnt) return;       // block-uniform
    int nt0 = blockIdx.y * 64;
    int t = threadIdx.x;                 // 256
    int g = t >> 6, nl = t & 63;
    int n = nt0 + nl;

    __shared__ int   prow[16];
    __shared__ int   pbase[16];
    __shared__ float Ws[16][64];         // [kk][n]
    __shared__ float Xs[16][20];         // [kk][pair], pad 4 (16B-aligned rows)

    if (t < 16) {
        int idx = chunk * 16 + t;
        int pk = (idx < cnt) ? pairtap[tap * 256 + idx] : -1;
        int row = pk >> 5;               // -1 stays negative
        prow[t] = (pk >= 0) ? row : -1;
        if (pk >= 0) {
            int b = row / KNBR;
            pbase[t] = ((b * NPOS + mut_pos[b]) * KNBR + (pk & 31)) * 400;
        } else pbase[t] = 0;
    }

    double binit = 0.0;
    if (tap == 4 && n < NTOT)
        binit = (double)(n < EMB ? b_f[n] : b_a[n - EMB]);
    double a0 = binit, a1 = binit, a2 = binit, a3 = binit;
    __syncthreads();

    int kkl = t >> 4, c4 = t & 15;       // staging roles
    for (int kb = 0; kb < KC; kb += 16) {
        // stage Ws: one float4 per thread
        {
            int nc = nt0 + c4 * 4;
            const float* wrow = Wp + (size_t)(tap * KC + kb + kkl) * NTOT;
            float4 w = make_float4(0.f, 0.f, 0.f, 0.f);
            if (nc + 3 < NTOT) w = *(const float4*)(wrow + nc);
            else {
                if (nc     < NTOT) w.x = wrow[nc];
                if (nc + 1 < NTOT) w.y = wrow[nc + 1];
                if (nc + 2 < NTOT) w.z = wrow[nc + 2];
            }
            *(float4*)&Ws[kkl][c4 * 4] = w;
        }
        // stage Xs: thread t -> (m = t>>4, kk = t&15)
        {
            int m = t >> 4, kk = t & 15;
            int row = prow[m];
            float xv = 0.0f;
            if (row >= 0) xv = etab[(size_t)pbase[m] + kb + kk];
            Xs[kk][m] = xv;
        }
        __syncthreads();
        #pragma unroll
        for (int kk = 0; kk < 16; ++kk) {
            double w = (double)Ws[kk][nl];
            float4 x4 = *(const float4*)&Xs[kk][g * 4];
            a0 += w * (double)x4.x;
            a1 += w * (double)x4.y;
            a2 += w * (double)x4.z;
            a3 += w * (double)x4.w;
        }
        __syncthreads();
    }
    if (n < NTOT) {
        int r0 = prow[g * 4 + 0], r1 = prow[g * 4 + 1];
        int r2 = prow[g * 4 + 2], r3 = prow[g * 4 + 3];
        if (r0 >= 0) atomicAdd(&C[(size_t)r0 * NTOT + n], a0);
        if (r1 >= 0) atomicAdd(&C[(size_t)r1 * NTOT + n], a1);
        if (r2 >= 0) atomicAdd(&C[(size_t)r2 * NTOT + n], a2);
        if (r3 >= 0) atomicAdd(&C[(size_t)r3 * NTOT + n], a3);
    }
}

// ---------------------------------------------------------------------------
// Kernel 5: per-(b,ch) softmax over m mask rows; la = o * softmax(att).
//  C layout: o = C[row][ch], att = C[row][484+ch].
// ---------------------------------------------------------------------------
__global__ void softmax_kernel(const double* __restrict__ C,
                               const int* __restrict__ mcount,
                               float* __restrict__ la) {
    int idx = blockIdx.x * blockDim.x + threadIdx.x;
    if (idx >= NB * EMB) return;
    int b = idx / EMB, ch = idx % EMB;
    int m = mcount[b];
    if (m == 0) return;
    float mx = -1e30f;
    for (int i = 0; i < m; ++i)
        mx = fmaxf(mx, (float)C[(size_t)(b * KNBR + i) * NTOT + EMB + ch]);
    double sum = 0.0;
    for (int i = 0; i < m; ++i)
        sum += (double)expf((float)C[(size_t)(b * KNBR + i) * NTOT + EMB + ch] - mx);
    for (int i = 0; i < m; ++i) {
        size_t o = (size_t)(b * KNBR + i) * NTOT;
        float w = (float)((double)expf((float)C[o + EMB + ch] - mx) / sum);
        la[(size_t)(b * KNBR + i) * EMB + ch] = (float)C[o + ch] * w;
    }
}

// ---------------------------------------------------------------------------
// Kernel 6: batched MLP GEMM (M=241 rows incl. zero bg row 240, K=N=484).
//  Input relu applied at load (both passes). mode 1: store raw f32 (y1).
//  mode 2: store ddg = y2 * w_ddg + b_ddg.
// ---------------------------------------------------------------------------
__global__ void mlp_gemm_kernel(const float* __restrict__ X,
                                const float* __restrict__ Wt,
                                const float* __restrict__ bias,
                                const float* __restrict__ wdd,
                                const float* __restrict__ bdd,
                                float* __restrict__ Y, int mode) {
    int m0  = blockIdx.x * 16;
    int nt0 = blockIdx.y * 64;
    int t = threadIdx.x;                 // 256
    int g = t >> 6, nl = t & 63;
    int n = nt0 + nl;
    __shared__ float Ws[16][64];
    __shared__ float Xs[16][20];
    double a0 = 0, a1 = 0, a2 = 0, a3 = 0;
    int kkl = t >> 4, c4 = t & 15;
    for (int kb = 0; kb < EMB; kb += 16) {
        {
            int k = kb + kkl;
            int nc = nt0 + c4 * 4;
            float4 w = make_float4(0.f, 0.f, 0.f, 0.f);
            if (k < EMB) {
                const float* wrow = Wt + (size_t)k * EMB;
                if (nc + 3 < EMB) w = *(const float4*)(wrow + nc);
                else {
                    if (nc     < EMB) w.x = wrow[nc];
                    if (nc + 1 < EMB) w.y = wrow[nc + 1];
                    if (nc + 2 < EMB) w.z = wrow[nc + 2];
                }
            }
            *(float4*)&Ws[kkl][c4 * 4] = w;
        }
        {
            int m = t >> 4, kk = t & 15;
            int row = m0 + m, k = kb + kk;
            float xv = 0.0f;
            if (row < MROWS && k < EMB)
                xv = fmaxf(X[(size_t)row * EMB + k], 0.0f);   // input relu
            Xs[kk][m] = xv;
        }
        __syncthreads();
        #pragma unroll
        for (int kk = 0; kk < 16; ++kk) {
            double w = (double)Ws[kk][nl];
            float4 x4 = *(const float4*)&Xs[kk][g * 4];
            a0 += w * (double)x4.x;
            a1 += w * (double)x4.y;
            a2 += w * (double)x4.z;
            a3 += w * (double)x4.w;
        }
        __syncthreads();
    }
    if (n < EMB) {
        double bs = (double)bias[n];
        double acc[4] = {a0, a1, a2, a3};
        for (int r = 0; r < 4; ++r) {
            int row = m0 + g * 4 + r;
            if (row >= MROWS) continue;
            float v = (float)(acc[r] + bs);
            if (mode == 2) v = v * wdd[0] + bdd[0];
            Y[(size_t)row * EMB + n] = v;
        }
    }
}

// ---------------------------------------------------------------------------
// Kernel 7: scores[b][s] = sum_j etab2[b, j, a, c_j]. 256 threads per (b,s).
// ---------------------------------------------------------------------------
__global__ void score_kernel(const int* __restrict__ sortc,
                             const int* __restrict__ seqs,
                             const int* __restrict__ mut_pos,
                             const int* __restrict__ rowidx,
                             const float* __restrict__ rows_all,
                             double* __restrict__ scoresD) {
    int blk = blockIdx.x;                 // 800 = 8 * 100
    int b = blk / STOT, s = blk % STOT;
    int mp = mut_pos[b];
    int a = (s < SMUT) ? sortc[((size_t)b * SMUT + s) * NPOS + mp]
                       : seqs[b * NPOS + mp];
    int t = threadIdx.x;                  // 256
    double acc = 0.0;
    for (int j = t; j < NPOS; j += 256) {
        int c = (s < SMUT) ? sortc[((size_t)b * SMUT + s) * NPOS + j]
                           : seqs[b * NPOS + j];
        int i = rowidx[b * NPOS + j];
        int row = (i >= 0) ? (b * KNBR + i) : (ROWS);  // bg = row 240
        acc += (double)rows_all[(size_t)row * EMB + a * H_PAD + c];
    }
    __shared__ double part[4];
    for (int off = 32; off > 0; off >>= 1)
        acc += __shfl_down(acc, off, 64);
    if ((t & 63) == 0) part[t >> 6] = acc;
    __syncthreads();
    if (t == 0) scoresD[blk] = part[0] + part[1] + part[2] + part[3];
}

// ---------------------------------------------------------------------------
// Kernel 8: out[b][s] = scores[b][s] - scores[b][WT],  s < 99
// ---------------------------------------------------------------------------
__global__ void final_kernel(const double* __restrict__ scoresD,
                             float* __restrict__ out) {
    int idx = blockIdx.x * blockDim.x + threadIdx.x;
    if (idx >= NB * SMUT) return;
    int b = idx / SMUT, s = idx % SMUT;
    out[idx] = (float)(scoresD[b * STOT + s] - scoresD[b * STOT + SMUT]);
}

// ---------------------------------------------------------------------------
extern "C" void kernel_launch(void* const* d_in, const int* in_sizes, int n_in,
                              void* d_out, int out_size, void* d_ws, size_t ws_size,
                              hipStream_t stream) {
    const float* etab = (const float*)d_in[0];
    const int*   E_idx = (const int*)d_in[1];
    const int*   sortc = (const int*)d_in[2];
    const int*   seqs  = (const int*)d_in[3];
    const int*   mutp  = (const int*)d_in[4];
    // d_in[5] = nodes (unused)
    const float* W_f = (const float*)d_in[6];
    const float* b_f = (const float*)d_in[7];
    const float* W_a = (const float*)d_in[8];
    const float* b_a = (const float*)d_in[9];
    const float* W1  = (const float*)d_in[10];
    const float* b1  = (const float*)d_in[11];
    const float* W2  = (const float*)d_in[12];
    const float* b2  = (const float*)d_in[13];
    const float* wdd = (const float*)d_in[14];
    const float* bdd = (const float*)d_in[15];
    float* out = (float*)d_out;

    char* wsb = (char*)d_ws;
    size_t off = 0;
    auto alloc = [&](size_t bytes) -> void* {
        void* p = wsb + off;
        off = (off + bytes + 255) & ~((size_t)255);
        return p;
    };
    // ---- zero-initialized region (single hipMemsetAsync) ----
    double* C       = (double*)alloc((size_t)ROWS * NTOT * 8);   // conv acc
    float*  la_buf  = (float*)alloc((size_t)MROWS * EMB * 4);    // zero + softmax rows
    int*    cnttap  = (int*)alloc(9 * 4);
    size_t zbytes = off;
    // ---- rest (fully overwritten every call) ----
    float*  Wp      = (float*)alloc((size_t)9 * KC * NTOT * 4);  // packed conv W
    float*  W1t     = (float*)alloc((size_t)EMB * EMB * 4);
    float*  W2t     = (float*)alloc((size_t)EMB * EMB * 4);
    int*    rowidx  = (int*)alloc((size_t)NB * NPOS * 4);
    int*    mcount  = (int*)alloc((size_t)NB * 4);
    int*    pairtap = (int*)alloc((size_t)9 * 256 * 4);
    float*  y1      = (float*)alloc((size_t)MROWS * EMB * 4);
    float*  rows_all= (float*)alloc((size_t)MROWS * EMB * 4);
    double* scoresD = (double*)alloc((size_t)NB * STOT * 8);
    (void)ws_size; (void)in_sizes; (void)n_in; (void)out_size;

    hipMemsetAsync(d_ws, 0, zbytes, stream);

    setup_kernel<<<NB, 512, 0, stream>>>(E_idx, mutp, etab, rowidx, mcount,
                                         pairtap, cnttap);

    {   // pack conv weights: c_src tiles x out tiles x {f,a}
        dim3 g((EMB * KSZ + 31) / 32, (EMB + 31) / 32, 2);
        pack_conv_kernel<<<g, dim3(32, 8), 0, stream>>>(W_f, W_a, Wp);
    }
    {   // W1,W2 transposes in one launch
        dim3 g((EMB + 31) / 32, (EMB + 31) / 32, 2);
        transpose_lin_kernel<<<g, dim3(32, 8), 0, stream>>>(W1, W2, W1t, W2t);
    }

    conv_gemm_kernel<<<dim3(9 * 15, 16), 256, 0, stream>>>(etab, Wp, b_f, b_a,
                                                           mutp, pairtap, cnttap, C);
    softmax_kernel<<<(NB * EMB + 255) / 256, 256, 0, stream>>>(C, mcount, la_buf);
    mlp_gemm_kernel<<<dim3((MROWS + 15) / 16, (EMB + 63) / 64), 256, 0, stream>>>(
        la_buf, W1t, b1, wdd, bdd, y1, 1);
    mlp_gemm_kernel<<<dim3((MROWS + 15) / 16, (EMB + 63) / 64), 256, 0, stream>>>(
        y1, W2t, b2, wdd, bdd, rows_all, 2);
    score_kernel<<<NB * STOT, 256, 0, stream>>>(sortc, seqs, mutp, rowidx,
                                                rows_all, scoresD);
    final_kernel<<<(NB * SMUT + 255) / 256, 256, 0, stream>>>(scoresD, out);
}

// Round 5
// 416.322 us; speedup vs baseline: 1.0204x; 1.0204x over previous
//
#include <hip/hip_runtime.h>
#include <math.h>

#define H_AA   20
#define H_PAD  22
#define EMB    484          // 22*22
#define KSZ    9
#define NB     8            // batch
#define NPOS   512          // n
#define KNBR   30           // k neighbors
#define SMUT   99
#define STOT   100          // SMUT + WT
#define ROWS   (NB*KNBR)    // 240
#define MROWS  241          // + background row
#define NTOT   968          // o(484) | att(484) fused N
#define KC     400          // real (unpadded) conv in-channels per tap
#define PT_CAP 256          // pairs per tap: GLOBAL across batches, <= 8*30=240
#define NCHUNK 15           // ceil(240/16) chunks of 16 pairs per tap

// ---------------------------------------------------------------------------
// Kernel 1: fused preprocessing. grid (137,16,5), block (32,8).
//  z=0/1: pack conv W{f,a}[out][in_pad*9+tap] -> Wp[tap*400+in_real][half*484+out]
//  z=2/3: transpose W1/W2 -> [in][out]
//  z=4  : zero C (f64 conv acc), la_buf, cnttap
// ---------------------------------------------------------------------------
__global__ void prep_kernel(const float* __restrict__ Wf,
                            const float* __restrict__ Wa,
                            float* __restrict__ Wp,
                            const float* __restrict__ W1,
                            const float* __restrict__ W2,
                            float* __restrict__ W1t,
                            float* __restrict__ W2t,
                            double* __restrict__ C,
                            float* __restrict__ la,
                            int* __restrict__ cnttap) {
    int z = blockIdx.z;
    if (z < 2) {
        const float* src = z ? Wa : Wf;
        int cb = blockIdx.x * 32;            // c_src tile (0..4355)
        int ob = blockIdx.y * 32;            // out tile  (0..483)
        __shared__ float tile[32][33];
        for (int yy = threadIdx.y; yy < 32; yy += 8) {
            int out = ob + yy, c = cb + threadIdx.x;
            if (out < EMB && c < EMB * KSZ)
                tile[yy][threadIdx.x] = src[(size_t)out * (EMB * KSZ) + c];
        }
        __syncthreads();
        for (int yy = threadIdx.y; yy < 32; yy += 8) {
            int c = cb + yy, out = ob + threadIdx.x;
            if (c < EMB * KSZ && out < EMB) {
                int tap = c % 9, in_pad = c / 9;
                int rr = in_pad / H_PAD, cc = in_pad % H_PAD;
                if (rr < H_AA && cc < H_AA) {
                    int k = tap * KC + rr * H_AA + cc;
                    Wp[(size_t)k * NTOT + z * EMB + out] = tile[threadIdx.x][yy];
                }
            }
        }
    } else if (z < 4) {
        if (blockIdx.x >= 16) return;
        const float* src = (z == 3) ? W2 : W1;
        float*       dst = (z == 3) ? W2t : W1t;
        __shared__ float tile[32][33];
        int c0 = blockIdx.x * 32, r0 = blockIdx.y * 32;
        for (int ty = threadIdx.y; ty < 32; ty += 8) {
            int r = r0 + ty, c = c0 + threadIdx.x;
            if (r < EMB && c < EMB) tile[ty][threadIdx.x] = src[(size_t)r * EMB + c];
        }
        __syncthreads();
        for (int ty = threadIdx.y; ty < 32; ty += 8) {
            int c = c0 + ty, r = r0 + threadIdx.x;
            if (r < EMB && c < EMB) dst[(size_t)c * EMB + r] = tile[threadIdx.x][ty];
        }
    } else {
        size_t id = (((size_t)blockIdx.y * 137 + blockIdx.x) * 256)
                    + threadIdx.y * 32 + threadIdx.x;
        const size_t NC = (size_t)ROWS * NTOT;        // 232320 doubles
        const size_t NL = (size_t)MROWS * EMB;        // 116644 floats
        if (id < NC) C[id] = 0.0;
        else if (id < NC + NL) la[id - NC] = 0.0f;
        if (id < 9) cnttap[id] = 0;
    }
}

// ---------------------------------------------------------------------------
// Kernel 2: per-batch setup. jmap in LDS, mask + ballot prefix-scan ->
// rowidx/mcount, pairs bucketed BY TAP (GLOBAL buckets shared by all 8
// batch-blocks -> up to 240 pairs/tap): pairtap[tap][idx] = (row_global<<5|j).
// cnttap zeroed by prep_kernel (stream-ordered before this).
// ---------------------------------------------------------------------------
__global__ void setup_kernel(const int* __restrict__ E_idx,
                             const int* __restrict__ mut_pos,
                             const float* __restrict__ etab,
                             int* __restrict__ rowidx_g,
                             int* __restrict__ mcount,
                             int* __restrict__ pairtap,
                             int* __restrict__ cnttap) {
    int b  = blockIdx.x;
    int mp = mut_pos[b];
    __shared__ int jmap[NPOS];
    __shared__ int wcnt[8], wbase[8];
    int t = threadIdx.x;                 // 512 threads
    jmap[t] = -1;
    __syncthreads();
    if (t < KNBR) {
        int nb = E_idx[(b * NPOS + mp) * KNBR + t];
        bool winner = true;
        for (int j2 = t + 1; j2 < KNBR; ++j2)
            if (E_idx[(b * NPOS + mp) * KNBR + j2] == nb) { winner = false; break; }
        if (winner) jmap[nb] = t;        // last-write-wins, unique per position
    }
    __syncthreads();
    int j = jmap[t];
    int f = 0;
    if (j >= 0) {
        float c0 = etab[(((size_t)(b * NPOS + mp)) * KNBR + j) * 400];
        f = (c0 != 0.0f) ? 1 : 0;        // mask = lin[:,:,0] != 0
    }
    unsigned long long bal = __ballot(f);
    int lane = t & 63, w = t >> 6;
    if (lane == 0) wcnt[w] = __popcll(bal);
    __syncthreads();
    if (t == 0) {
        int s = 0;
        for (int ww = 0; ww < 8; ++ww) { wbase[ww] = s; s += wcnt[ww]; }
        mcount[b] = s;
    }
    __syncthreads();
    int ridx = -1;
    if (f) ridx = wbase[w] + __popcll(bal & ((1ull << lane) - 1ull));
    rowidx_g[b * NPOS + t] = ridx;
    if (f) {
        int row = b * KNBR + ridx;       // global row id 0..239
        for (int d = -4; d <= 4; ++d) {
            int q = t + d;
            if (q < 0 || q >= NPOS) continue;
            int jq = jmap[q];
            if (jq < 0) continue;        // conv input needs scatter-presence, not mask
            int tap = d + 4;
            int idx = atomicAdd(&cnttap[tap], 1);
            pairtap[tap * PT_CAP + idx] = (row << 5) | jq;
        }
    }
}

// ---------------------------------------------------------------------------
// Kernel 3: conv GEMM, bucketed by tap. grid (9*15 chunks, 16 n-tiles), 256 thr.
//  f32 inner accumulators (final-output error ~1e-6 after MLP attenuation,
//  threshold 7.9e-5), f64 atomicAdd into zeroed C[240][968].
//  Bias folded in at tap==4 (each masked row has exactly one tap-4 pair).
// ---------------------------------------------------------------------------
__global__ void conv_gemm_kernel(const float* __restrict__ etab,
                                 const float* __restrict__ Wp,
                                 const float* __restrict__ b_f,
                                 const float* __restrict__ b_a,
                                 const int* __restrict__ mut_pos,
                                 const int* __restrict__ pairtap,
                                 const int* __restrict__ cnttap,
                                 double* __restrict__ C) {
    int tap   = blockIdx.x / NCHUNK;
    int chunk = blockIdx.x % NCHUNK;
    int cnt = cnttap[tap];
    if (chunk * 16 >= cnt) return;       // block-uniform
    int nt0 = blockIdx.y * 64;
    int t = threadIdx.x;                 // 256
    int g = t >> 6, nl = t & 63;
    int n = nt0 + nl;

    __shared__ int   prow[16];
    __shared__ int   pbase[16];
    __shared__ float Ws[16][64];         // [kk][n]
    __shared__ float Xs[16][20];         // [kk][pair], pad 4 (16B-aligned rows)

    if (t < 16) {
        int idx = chunk * 16 + t;
        int pk = (idx < cnt) ? pairtap[tap * PT_CAP + idx] : -1;
        int row = pk >> 5;
        prow[t] = (pk >= 0) ? row : -1;
        if (pk >= 0) {
            int b = row / KNBR;
            pbase[t] = ((b * NPOS + mut_pos[b]) * KNBR + (pk & 31)) * 400;
        } else pbase[t] = 0;
    }
    float a0 = 0.f, a1 = 0.f, a2 = 0.f, a3 = 0.f;
    __syncthreads();

    int kkl = t >> 4, c4 = t & 15;       // staging roles
    for (int kb = 0; kb < KC; kb += 16) {
        {   // stage Ws: one float4 per thread
            int nc = nt0 + c4 * 4;
            const float* wrow = Wp + (size_t)(tap * KC + kb + kkl) * NTOT;
            float4 w = make_float4(0.f, 0.f, 0.f, 0.f);
            if (nc + 3 < NTOT) w = *(const float4*)(wrow + nc);
            else {
                if (nc     < NTOT) w.x = wrow[nc];
                if (nc + 1 < NTOT) w.y = wrow[nc + 1];
                if (nc + 2 < NTOT) w.z = wrow[nc + 2];
            }
            *(float4*)&Ws[kkl][c4 * 4] = w;
        }
        {   // stage Xs
            int m = t >> 4, kk = t & 15;
            int row = prow[m];
            float xv = 0.0f;
            if (row >= 0) xv = etab[(size_t)pbase[m] + kb + kk];
            Xs[kk][m] = xv;
        }
        __syncthreads();
        #pragma unroll
        for (int kk = 0; kk < 16; ++kk) {
            float w = Ws[kk][nl];
            float4 x4 = *(const float4*)&Xs[kk][g * 4];
            a0 += w * x4.x; a1 += w * x4.y;
            a2 += w * x4.z; a3 += w * x4.w;
        }
        __syncthreads();
    }
    if (n < NTOT) {
        double binit = 0.0;
        if (tap == 4)
            binit = (double)(n < EMB ? b_f[n] : b_a[n - EMB]);
        int r0 = prow[g * 4 + 0], r1 = prow[g * 4 + 1];
        int r2 = prow[g * 4 + 2], r3 = prow[g * 4 + 3];
        if (r0 >= 0) atomicAdd(&C[(size_t)r0 * NTOT + n], (double)a0 + binit);
        if (r1 >= 0) atomicAdd(&C[(size_t)r1 * NTOT + n], (double)a1 + binit);
        if (r2 >= 0) atomicAdd(&C[(size_t)r2 * NTOT + n], (double)a2 + binit);
        if (r3 >= 0) atomicAdd(&C[(size_t)r3 * NTOT + n], (double)a3 + binit);
    }
}

// ---------------------------------------------------------------------------
// Kernel 4: per-(b,ch) softmax over m mask rows; la = o * softmax(att).
// ---------------------------------------------------------------------------
__global__ void softmax_kernel(const double* __restrict__ C,
                               const int* __restrict__ mcount,
                               float* __restrict__ la) {
    int idx = blockIdx.x * blockDim.x + threadIdx.x;
    if (idx >= NB * EMB) return;
    int b = idx / EMB, ch = idx % EMB;
    int m = mcount[b];
    if (m == 0) return;
    float mx = -1e30f;
    for (int i = 0; i < m; ++i)
        mx = fmaxf(mx, (float)C[(size_t)(b * KNBR + i) * NTOT + EMB + ch]);
    double sum = 0.0;
    for (int i = 0; i < m; ++i)
        sum += (double)expf((float)C[(size_t)(b * KNBR + i) * NTOT + EMB + ch] - mx);
    for (int i = 0; i < m; ++i) {
        size_t o = (size_t)(b * KNBR + i) * NTOT;
        float w = (float)((double)expf((float)C[o + EMB + ch] - mx) / sum);
        la[(size_t)(b * KNBR + i) * EMB + ch] = (float)C[o + ch] * w;
    }
}

// ---------------------------------------------------------------------------
// Kernel 5: batched MLP GEMM (M=241 rows incl. zero bg row 240, K=N=484).
//  Input relu at load. mode 1: f32 accum, store y1. mode 2: f64 accum
//  (rows_out errors are amplified ~100x by score-slot reuse), store ddg.
// ---------------------------------------------------------------------------
__global__ void mlp_gemm_kernel(const float* __restrict__ X,
                                const float* __restrict__ Wt,
                                const float* __restrict__ bias,
                                const float* __restrict__ wdd,
                                const float* __restrict__ bdd,
                                float* __restrict__ Y, int mode) {
    int m0  = blockIdx.x * 16;
    int nt0 = blockIdx.y * 64;
    int t = threadIdx.x;                 // 256
    int g = t >> 6, nl = t & 63;
    int n = nt0 + nl;
    __shared__ float Ws[16][64];
    __shared__ float Xs[16][20];
    double d0 = 0, d1 = 0, d2 = 0, d3 = 0;
    float  f0 = 0, f1 = 0, f2 = 0, f3 = 0;
    int kkl = t >> 4, c4 = t & 15;
    for (int kb = 0; kb < EMB; kb += 16) {
        {
            int k = kb + kkl;
            int nc = nt0 + c4 * 4;
            float4 w = make_float4(0.f, 0.f, 0.f, 0.f);
            if (k < EMB) {
                const float* wrow = Wt + (size_t)k * EMB;
                if (nc + 3 < EMB) w = *(const float4*)(wrow + nc);
                else {
                    if (nc     < EMB) w.x = wrow[nc];
                    if (nc + 1 < EMB) w.y = wrow[nc + 1];
                    if (nc + 2 < EMB) w.z = wrow[nc + 2];
                }
            }
            *(float4*)&Ws[kkl][c4 * 4] = w;
        }
        {
            int m = t >> 4, kk = t & 15;
            int row = m0 + m, k = kb + kk;
            float xv = 0.0f;
            if (row < MROWS && k < EMB)
                xv = fmaxf(X[(size_t)row * EMB + k], 0.0f);   // input relu
            Xs[kk][m] = xv;
        }
        __syncthreads();
        if (mode == 1) {
            #pragma unroll
            for (int kk = 0; kk < 16; ++kk) {
                float w = Ws[kk][nl];
                float4 x4 = *(const float4*)&Xs[kk][g * 4];
                f0 += w * x4.x; f1 += w * x4.y;
                f2 += w * x4.z; f3 += w * x4.w;
            }
        } else {
            #pragma unroll
            for (int kk = 0; kk < 16; ++kk) {
                double w = (double)Ws[kk][nl];
                float4 x4 = *(const float4*)&Xs[kk][g * 4];
                d0 += w * (double)x4.x; d1 += w * (double)x4.y;
                d2 += w * (double)x4.z; d3 += w * (double)x4.w;
            }
        }
        __syncthreads();
    }
    if (n < EMB) {
        double bs = (double)bias[n];
        double acc[4];
        if (mode == 1) { acc[0]=f0; acc[1]=f1; acc[2]=f2; acc[3]=f3; }
        else           { acc[0]=d0; acc[1]=d1; acc[2]=d2; acc[3]=d3; }
        for (int r = 0; r < 4; ++r) {
            int row = m0 + g * 4 + r;
            if (row >= MROWS) continue;
            float v = (float)(acc[r] + bs);
            if (mode == 2) v = v * wdd[0] + bdd[0];
            Y[(size_t)row * EMB + n] = v;
        }
    }
}

// ---------------------------------------------------------------------------
// Kernel 6: scores[b][s] = sum_j etab2[b, j, a, c_j]. 256 threads per (b,s).
// ---------------------------------------------------------------------------
__global__ void score_kernel(const int* __restrict__ sortc,
                             const int* __restrict__ seqs,
                             const int* __restrict__ mut_pos,
                             const int* __restrict__ rowidx,
                             const float* __restrict__ rows_all,
                             double* __restrict__ scoresD) {
    int blk = blockIdx.x;                 // 800 = 8 * 100
    int b = blk / STOT, s = blk % STOT;
    int mp = mut_pos[b];
    int a = (s < SMUT) ? sortc[((size_t)b * SMUT + s) * NPOS + mp]
                       : seqs[b * NPOS + mp];
    int t = threadIdx.x;                  // 256
    double acc = 0.0;
    for (int j = t; j < NPOS; j += 256) {
        int c = (s < SMUT) ? sortc[((size_t)b * SMUT + s) * NPOS + j]
                           : seqs[b * NPOS + j];
        int i = rowidx[b * NPOS + j];
        int row = (i >= 0) ? (b * KNBR + i) : (ROWS);  // bg = row 240
        acc += (double)rows_all[(size_t)row * EMB + a * H_PAD + c];
    }
    __shared__ double part[4];
    for (int off = 32; off > 0; off >>= 1)
        acc += __shfl_down(acc, off, 64);
    if ((t & 63) == 0) part[t >> 6] = acc;
    __syncthreads();
    if (t == 0) scoresD[blk] = part[0] + part[1] + part[2] + part[3];
}

// ---------------------------------------------------------------------------
// Kernel 7: out[b][s] = scores[b][s] - scores[b][WT],  s < 99
// ---------------------------------------------------------------------------
__global__ void final_kernel(const double* __restrict__ scoresD,
                             float* __restrict__ out) {
    int idx = blockIdx.x * blockDim.x + threadIdx.x;
    if (idx >= NB * SMUT) return;
    int b = idx / SMUT, s = idx % SMUT;
    out[idx] = (float)(scoresD[b * STOT + s] - scoresD[b * STOT + SMUT]);
}

// ---------------------------------------------------------------------------
extern "C" void kernel_launch(void* const* d_in, const int* in_sizes, int n_in,
                              void* d_out, int out_size, void* d_ws, size_t ws_size,
                              hipStream_t stream) {
    const float* etab = (const float*)d_in[0];
    const int*   E_idx = (const int*)d_in[1];
    const int*   sortc = (const int*)d_in[2];
    const int*   seqs  = (const int*)d_in[3];
    const int*   mutp  = (const int*)d_in[4];
    // d_in[5] = nodes (unused)
    const float* W_f = (const float*)d_in[6];
    const float* b_f = (const float*)d_in[7];
    const float* W_a = (const float*)d_in[8];
    const float* b_a = (const float*)d_in[9];
    const float* W1  = (const float*)d_in[10];
    const float* b1  = (const float*)d_in[11];
    const float* W2  = (const float*)d_in[12];
    const float* b2  = (const float*)d_in[13];
    const float* wdd = (const float*)d_in[14];
    const float* bdd = (const float*)d_in[15];
    float* out = (float*)d_out;

    char* wsb = (char*)d_ws;
    size_t off = 0;
    auto alloc = [&](size_t bytes) -> void* {
        void* p = wsb + off;
        off = (off + bytes + 255) & ~((size_t)255);
        return p;
    };
    double* C       = (double*)alloc((size_t)ROWS * NTOT * 8);   // conv acc (zeroed by prep)
    float*  la_buf  = (float*)alloc((size_t)MROWS * EMB * 4);    // zeroed by prep
    int*    cnttap  = (int*)alloc(9 * 4);                        // zeroed by prep
    float*  Wp      = (float*)alloc((size_t)9 * KC * NTOT * 4);  // packed conv W
    float*  W1t     = (float*)alloc((size_t)EMB * EMB * 4);
    float*  W2t     = (float*)alloc((size_t)EMB * EMB * 4);
    int*    rowidx  = (int*)alloc((size_t)NB * NPOS * 4);
    int*    mcount  = (int*)alloc((size_t)NB * 4);
    int*    pairtap = (int*)alloc((size_t)9 * PT_CAP * 4);
    float*  y1      = (float*)alloc((size_t)MROWS * EMB * 4);
    float*  rows_all= (float*)alloc((size_t)MROWS * EMB * 4);
    double* scoresD = (double*)alloc((size_t)NB * STOT * 8);
    (void)ws_size; (void)in_sizes; (void)n_in; (void)out_size;

    {   // fused: pack conv W (z=0/1), transpose W1/W2 (z=2/3), zero-init (z=4)
        dim3 g((EMB * KSZ + 31) / 32, 16, 5);
        prep_kernel<<<g, dim3(32, 8), 0, stream>>>(W_f, W_a, Wp, W1, W2, W1t, W2t,
                                                   C, la_buf, cnttap);
    }
    setup_kernel<<<NB, 512, 0, stream>>>(E_idx, mutp, etab, rowidx, mcount,
                                         pairtap, cnttap);
    conv_gemm_kernel<<<dim3(9 * NCHUNK, 16), 256, 0, stream>>>(etab, Wp, b_f, b_a,
                                                               mutp, pairtap, cnttap, C);
    softmax_kernel<<<(NB * EMB + 255) / 256, 256, 0, stream>>>(C, mcount, la_buf);
    mlp_gemm_kernel<<<dim3((MROWS + 15) / 16, (EMB + 63) / 64), 256, 0, stream>>>(
        la_buf, W1t, b1, wdd, bdd, y1, 1);
    mlp_gemm_kernel<<<dim3((MROWS + 15) / 16, (EMB + 63) / 64), 256, 0, stream>>>(
        y1, W2t, b2, wdd, bdd, rows_all, 2);
    score_kernel<<<NB * STOT, 256, 0, stream>>>(sortc, seqs, mutp, rowidx,
                                                rows_all, scoresD);
    final_kernel<<<(NB * SMUT + 255) / 256, 256, 0, stream>>>(scoresD, out);
}